// Round 5
// baseline (69.302 us; speedup 1.0000x reference)
//
#include <hip/hip_runtime.h>

// out[b,c,d,h,w] = in[b,0,d, clamp(h+dy,0,H-1), clamp(w+dx,0,W-1)]
// (dy,dx): c0:(-1,-1) c1:(0,0) c2:(+1,+1) c3:(+1,-1) c4:(-1,+1)
// B=2, D=48, H=256, W=512 f32.
//
// R5: software-pipelined h-tiles. R4's model: grid fully resident -> all
// waves issue all loads before any store -> HBM does a serial read phase
// (~9us) then a write phase (~36us). Fix: NIT=4 tiles/thread with explicit
// 2-deep register double-buffer: loads of tile k+1 issue before stores of
// tile k, so reads hide under the store drain in steady state.

typedef float f32x4 __attribute__((ext_vector_type(4)));

constexpr int D = 48, H = 256, W = 512;
constexpr int W4 = W / 4;     // 128: two waves cover one full row
constexpr int HB = 4;         // output rows per thread per tile
constexpr int NIT = 4;        // tiles per thread (pipelined)
constexpr int WIN = HB + 2;   // window rows per tile

__device__ __forceinline__ void nt_store4(float* p, float a, float b, float c, float d) {
    f32x4 v = {a, b, c, d};
    __builtin_nontemporal_store(v, reinterpret_cast<f32x4*>(p));
}

__device__ __forceinline__ void load_win(const float* __restrict__ base,
                                         int h0, int w0, float4 (&v)[WIN]) {
    #pragma unroll
    for (int i = 0; i < WIN; ++i) {
        int r = h0 - 1 + i;
        r = r < 0 ? 0 : (r > H - 1 ? H - 1 : r);
        v[i] = *reinterpret_cast<const float4*>(base + r * W + w0);
    }
}

__device__ __forceinline__ void finish_store(const float* __restrict__ base,
                                             float* __restrict__ obase,
                                             int planeDHW, int h0, int w0,
                                             int w4, int lane,
                                             const float4 (&v)[WIN]) {
    // L/R halo via intra-wave shuffle; seam lanes fall back to an L1-hit load.
    float L[WIN], R[WIN];
    #pragma unroll
    for (int i = 0; i < WIN; ++i) {
        int r = h0 - 1 + i;
        r = r < 0 ? 0 : (r > H - 1 ? H - 1 : r);
        const float* row = base + r * W;
        float l  = __shfl_up(v[i].w, 1);
        float rr = __shfl_down(v[i].x, 1);
        if (w4 == 0)          l  = v[i].x;
        else if (lane == 0)   l  = row[w0 - 1];
        if (w4 == W4 - 1)     rr = v[i].w;
        else if (lane == 63)  rr = row[w0 + 4];
        L[i] = l; R[i] = rr;
    }

    float* o0 = obase + h0 * W;
    #pragma unroll
    for (int j = 0; j < HB; ++j) {  // c0: row h-1, w-1..w+2
        nt_store4(o0 + j * W, L[j], v[j].x, v[j].y, v[j].z);
    }
    #pragma unroll
    for (int j = 0; j < HB; ++j) {  // c1: row h, w..w+3
        nt_store4(o0 + planeDHW + j * W, v[j+1].x, v[j+1].y, v[j+1].z, v[j+1].w);
    }
    #pragma unroll
    for (int j = 0; j < HB; ++j) {  // c2: row h+1, w+1..w+4
        nt_store4(o0 + 2 * planeDHW + j * W, v[j+2].y, v[j+2].z, v[j+2].w, R[j+2]);
    }
    #pragma unroll
    for (int j = 0; j < HB; ++j) {  // c3: row h+1, w-1..w+2
        nt_store4(o0 + 3 * planeDHW + j * W, L[j+2], v[j+2].x, v[j+2].y, v[j+2].z);
    }
    #pragma unroll
    for (int j = 0; j < HB; ++j) {  // c4: row h-1, w+1..w+4
        nt_store4(o0 + 4 * planeDHW + j * W, v[j].y, v[j].z, v[j].w, R[j]);
    }
}

__global__ __launch_bounds__(256) void prop_kernel(
    const float* __restrict__ in, float* __restrict__ out) {
    const int w4   = threadIdx.x & (W4 - 1);   // 0..127
    const int hgrp = threadIdx.x >> 7;         // 0..1
    const int lane = threadIdx.x & 63;

    int blk = blockIdx.x;
    const int hq = blk & 7;                    // 8 h-quads of 32 rows
    blk >>= 3;
    const int d = blk % D;
    const int b = blk / D;

    const int w0 = w4 * 4;
    const float* base = in + (b * D + d) * (H * W);
    const int planeDHW = D * H * W;
    float* obase = out + (b * 5 * D + d) * (H * W) + w0;

    // h0 for tile it: hq*32 + it*8 + hgrp*4
    float4 vA[WIN], vB[WIN];
    load_win(base, hq * 32 + hgrp * HB, w0, vA);

    #pragma unroll
    for (int it = 0; it < NIT; ++it) {
        const int h0c = hq * 32 + it * 8 + hgrp * HB;
        const int h0n = h0c + 8;
        if ((it & 1) == 0) {
            if (it < NIT - 1) load_win(base, h0n, w0, vB);   // prefetch next
            finish_store(base, obase, planeDHW, h0c, w0, w4, lane, vA);
        } else {
            if (it < NIT - 1) load_win(base, h0n, w0, vA);   // prefetch next
            finish_store(base, obase, planeDHW, h0c, w0, w4, lane, vB);
        }
    }
}

extern "C" void kernel_launch(void* const* d_in, const int* in_sizes, int n_in,
                              void* d_out, int out_size, void* d_ws, size_t ws_size,
                              hipStream_t stream) {
    const float* in = (const float*)d_in[0];
    float* out = (float*)d_out;

    // grid: B * D * (H/32) = 2 * 48 * 8 = 768 blocks = exactly 3 per CU
    const int grid = 2 * D * (H / (2 * HB * NIT));
    prop_kernel<<<grid, 256, 0, stream>>>(in, out);
}

// Round 6
// 65.242 us; speedup vs baseline: 1.0622x; 1.0622x over previous
//
#include <hip/hip_runtime.h>

// out[b,c,d,h,w] = in[b,0,d, clamp(h+dy,0,H-1), clamp(w+dx,0,W-1)]
// (dy,dx): c0:(-1,-1) c1:(0,0) c2:(+1,+1) c3:(+1,-1) c4:(-1,+1)
// B=2, D=48, H=256, W=512 f32.
//
// R6 = R4 with ONE change: plain stores instead of nontemporal (A/B test).
// The 7.0 TB/s fill kernel uses plain stores; full-line writes are
// write-combined in L2 without read-allocate, and nt may bypass coalescing
// paths. Everything else identical to R4 (53.5 us): HB=8 rows/thread,
// 10 window-row loads -> 40 float4 stores, channel-major store order.

typedef float f32x4 __attribute__((ext_vector_type(4)));

constexpr int D = 48, H = 256, W = 512;
constexpr int W4 = W / 4;     // 128: two waves cover one full row
constexpr int HB = 8;         // output rows per thread

__device__ __forceinline__ void store4(float* p, float a, float b, float c, float d) {
    f32x4 v = {a, b, c, d};
    *reinterpret_cast<f32x4*>(p) = v;
}

__global__ __launch_bounds__(256) void prop_kernel(
    const float* __restrict__ in, float* __restrict__ out) {
    const int w4   = threadIdx.x & (W4 - 1);   // 0..127
    const int hgrp = threadIdx.x >> 7;         // 0..1 (two h-groups per block)
    const int lane = threadIdx.x & 63;

    int blk = blockIdx.x;
    const int h16 = blk & 15;                  // H / (2*HB) = 16 h-blocks
    blk >>= 4;
    const int d = blk % D;
    const int b = blk / D;

    const int h0 = h16 * (2 * HB) + hgrp * HB; // first output row
    const int w0 = w4 * 4;

    const float* base = in + (b * D + d) * (H * W);

    // Load (HB+2)-row window [h0-1 .. h0+HB] (clamped); L/R halo via shuffle.
    float4 v[HB + 2];
    float  L[HB + 2], R[HB + 2];
    #pragma unroll
    for (int i = 0; i < HB + 2; ++i) {
        int r = h0 - 1 + i;
        r = r < 0 ? 0 : (r > H - 1 ? H - 1 : r);
        const float* row = base + r * W;
        float4 t = *reinterpret_cast<const float4*>(row + w0);
        float l  = __shfl_up(t.w, 1);          // lane i-1's w0+3 == our w0-1
        float rr = __shfl_down(t.x, 1);        // lane i+1's w0   == our w0+4
        if (w4 == 0)          l  = t.x;        // clamp at W edge
        else if (lane == 0)   l  = row[w0 - 1];    // wave seam fallback
        if (w4 == W4 - 1)     rr = t.w;        // clamp at W edge
        else if (lane == 63)  rr = row[w0 + 4];    // wave seam fallback
        v[i] = t; L[i] = l; R[i] = rr;
    }

    const int planeDHW = D * H * W;            // 6,291,456
    float* o0 = out + ((b * 5) * D + d) * (H * W) + h0 * W + w0;

    // Channel-major stores: per channel, HB consecutive rows (contiguous
    // 1KB/wave lines, 8KB burst per stream) before switching streams.
    #pragma unroll
    for (int j = 0; j < HB; ++j) {  // c0: row h-1, w-1..w+2
        store4(o0 + j * W, L[j], v[j].x, v[j].y, v[j].z);
    }
    #pragma unroll
    for (int j = 0; j < HB; ++j) {  // c1: row h, w..w+3
        store4(o0 + planeDHW + j * W, v[j+1].x, v[j+1].y, v[j+1].z, v[j+1].w);
    }
    #pragma unroll
    for (int j = 0; j < HB; ++j) {  // c2: row h+1, w+1..w+4
        store4(o0 + 2 * planeDHW + j * W, v[j+2].y, v[j+2].z, v[j+2].w, R[j+2]);
    }
    #pragma unroll
    for (int j = 0; j < HB; ++j) {  // c3: row h+1, w-1..w+2
        store4(o0 + 3 * planeDHW + j * W, L[j+2], v[j+2].x, v[j+2].y, v[j+2].z);
    }
    #pragma unroll
    for (int j = 0; j < HB; ++j) {  // c4: row h-1, w+1..w+4
        store4(o0 + 4 * planeDHW + j * W, v[j].y, v[j].z, v[j].w, R[j]);
    }
}

extern "C" void kernel_launch(void* const* d_in, const int* in_sizes, int n_in,
                              void* d_out, int out_size, void* d_ws, size_t ws_size,
                              hipStream_t stream) {
    const float* in = (const float*)d_in[0];
    float* out = (float*)d_out;

    // grid: B * D * (H / 16) = 2 * 48 * 16 = 1536 blocks, exact cover
    const int grid = 2 * D * (H / (2 * HB));
    prop_kernel<<<grid, 256, 0, stream>>>(in, out);
}